// Round 12
// baseline (521.663 us; speedup 1.0000x reference)
//
#include <hip/hip_runtime.h>
#include <hip/hip_cooperative_groups.h>

namespace cg = cooperative_groups;

#define NV 20000
#define NC 300
#define NI 10000
#define NN 30300   // NV + NC + NI
#define NE 1000000
#define D  64

#define NB     512          // buckets for CSR build
#define BNODES 60           // ceil(NN / NB); 512*60 = 30720 >= 30300
#define CAP    2560         // per-bucket edge capacity (mean 1980, +13 sigma)
#define BIN_CHUNK 2048
#define NBLK_BIN ((NE + BIN_CHUNK - 1) / BIN_CHUNK)   // 489
#define COOP_BLOCKS 1024    // 4 blocks/CU x 256 CUs -> co-resident

__device__ __forceinline__ unsigned short f2bf(float x) {
    unsigned u = __float_as_uint(x);
    u += 0x7FFFu + ((u >> 16) & 1u);
    return (unsigned short)(u >> 16);
}

// ---- fused: all_off=relu(concat) as bf16 bits; zero out[:NV*D]; bin edges -------
__global__ void init_bin_kernel(const float4* __restrict__ vo, const float4* __restrict__ co,
                                const float4* __restrict__ io, unsigned short* __restrict__ buf,
                                float4* __restrict__ outz,
                                const int* __restrict__ head, const int* __restrict__ tail,
                                int* __restrict__ gcur, unsigned* __restrict__ pairs) {
    __shared__ int hist[NB];
    __shared__ int base[NB];
    int t = threadIdx.x;
    int i = blockIdx.x * 256 + t;
    // ---- init slice ----
    if (i < NN * 16) {
        if (i < NV * 16) outz[i] = make_float4(0.f, 0.f, 0.f, 0.f);
        int n = i >> 4;
        float4 v;
        if (n < NV)            v = vo[i];
        else if (n < NV + NC)  v = co[i - NV * 16];
        else                   v = io[i - (NV + NC) * 16];
        ushort4 o;
        o.x = f2bf(fmaxf(v.x, 0.f));
        o.y = f2bf(fmaxf(v.y, 0.f));
        o.z = f2bf(fmaxf(v.z, 0.f));
        o.w = f2bf(fmaxf(v.w, 0.f));
        *reinterpret_cast<ushort4*>(buf + (size_t)i * 4) = o;
    }
    // ---- bin slice (blocks 0..NBLK_BIN-1) ----
    if (blockIdx.x >= NBLK_BIN) return;
    int e0 = blockIdx.x * BIN_CHUNK;
    for (int j = t; j < NB; j += 256) hist[j] = 0;
    __syncthreads();
    int hs[8], ts[8];
    if (e0 + BIN_CHUNK <= NE) {
        const int4* h4 = reinterpret_cast<const int4*>(head + e0);
        const int4* t4 = reinterpret_cast<const int4*>(tail + e0);
        int4 ha = h4[t], hb = h4[256 + t];
        int4 ta = t4[t], tb = t4[256 + t];
        hs[0] = ha.x; hs[1] = ha.y; hs[2] = ha.z; hs[3] = ha.w;
        hs[4] = hb.x; hs[5] = hb.y; hs[6] = hb.z; hs[7] = hb.w;
        ts[0] = ta.x; ts[1] = ta.y; ts[2] = ta.z; ts[3] = ta.w;
        ts[4] = tb.x; ts[5] = tb.y; ts[6] = tb.z; ts[7] = tb.w;
#pragma unroll
        for (int k = 0; k < 8; k++) atomicAdd(&hist[hs[k] / BNODES], 1);
    } else {
#pragma unroll
        for (int k = 0; k < 8; k++) {
            int e = e0 + k * 256 + t;
            if (e < NE) {
                hs[k] = head[e]; ts[k] = tail[e];
                atomicAdd(&hist[hs[k] / BNODES], 1);
            } else hs[k] = -1;
        }
    }
    __syncthreads();
    for (int j = t; j < NB; j += 256) {
        int c = hist[j];
        base[j] = c ? atomicAdd(&gcur[j], c) : 0;
        hist[j] = 0;
    }
    __syncthreads();
#pragma unroll
    for (int k = 0; k < 8; k++) {
        if (hs[k] >= 0) {
            int b = hs[k] / BNODES;
            int pos = base[b] + atomicAdd(&hist[b], 1);
            if (pos < CAP)
                pairs[(size_t)b * CAP + pos] = ((unsigned)hs[k] << 15) | (unsigned)ts[k];
        }
    }
}

// ---- hop body: segmented max/min on bf16 bits, 16B/lane, 8 edges/round ----------
template<bool F32OUT>
__device__ __forceinline__ void hop_node(int wid, int lane,
        const unsigned short* __restrict__ prev,
        const int* __restrict__ starts, const int* __restrict__ ends,
        const unsigned short* __restrict__ stails, void* __restrict__ outp, int nNodes) {
    if (wid >= nNodes) return;
    int start = starts[wid], end = ends[wid];
    bool isMin = (!F32OUT) && (wid >= NV + NC);
    unsigned mm = isMin ? 0xFFFFFFFFu : 0u;
    int grp = lane >> 3, sub = lane & 7;
    const unsigned short* rowb = prev + sub * 8;
    unsigned a0 = 0, a1 = 0, a2 = 0, a3 = 0, a4 = 0, a5 = 0, a6 = 0, a7 = 0;
    for (int base = start; base < end; base += 64) {
        int cdeg = end - base; if (cdeg > 64) cdeg = 64;
        int tv = (lane < cdeg) ? (int)stails[base + lane] : 0;
        for (int r0 = 0; r0 < cdeg; r0 += 32) {
#pragma unroll
            for (int r = 0; r < 4; ++r) {
                int e  = r0 + r * 8 + grp;
                int ec = (e < cdeg) ? e : (cdeg - 1);
                int tix = __shfl(tv, ec);
                uint4 v = *reinterpret_cast<const uint4*>(rowb + tix * D);
                unsigned live = (e < cdeg) ? 0xFFFFFFFFu : 0u;
                v.x = (v.x ^ mm) & live; v.y = (v.y ^ mm) & live;
                v.z = (v.z ^ mm) & live; v.w = (v.w ^ mm) & live;
                a0 = max(a0, v.x & 0xFFFFu); a1 = max(a1, v.x >> 16);
                a2 = max(a2, v.y & 0xFFFFu); a3 = max(a3, v.y >> 16);
                a4 = max(a4, v.z & 0xFFFFu); a5 = max(a5, v.z >> 16);
                a6 = max(a6, v.w & 0xFFFFu); a7 = max(a7, v.w >> 16);
            }
        }
    }
#pragma unroll
    for (int d = 8; d < 64; d <<= 1) {
        a0 = max(a0, (unsigned)__shfl_xor((int)a0, d));
        a1 = max(a1, (unsigned)__shfl_xor((int)a1, d));
        a2 = max(a2, (unsigned)__shfl_xor((int)a2, d));
        a3 = max(a3, (unsigned)__shfl_xor((int)a3, d));
        a4 = max(a4, (unsigned)__shfl_xor((int)a4, d));
        a5 = max(a5, (unsigned)__shfl_xor((int)a5, d));
        a6 = max(a6, (unsigned)__shfl_xor((int)a6, d));
        a7 = max(a7, (unsigned)__shfl_xor((int)a7, d));
    }
    unsigned m16 = mm & 0xFFFFu;
    unsigned r0v = a0 ^ m16, r1v = a1 ^ m16, r2v = a2 ^ m16, r3v = a3 ^ m16;
    unsigned r4v = a4 ^ m16, r5v = a5 ^ m16, r6v = a6 ^ m16, r7v = a7 ^ m16;
    if (start >= end) { r0v=r1v=r2v=r3v=r4v=r5v=r6v=r7v=0; }
    if (grp == 0) {
        if (F32OUT) {
            float4 oa = make_float4(__uint_as_float(r0v << 16), __uint_as_float(r1v << 16),
                                    __uint_as_float(r2v << 16), __uint_as_float(r3v << 16));
            float4 ob = make_float4(__uint_as_float(r4v << 16), __uint_as_float(r5v << 16),
                                    __uint_as_float(r6v << 16), __uint_as_float(r7v << 16));
            float4* op = reinterpret_cast<float4*>(outp) + (size_t)wid * 16 + sub * 2;
            op[0] = oa; op[1] = ob;
        } else {
            uint4 o;
            o.x = r0v | (r1v << 16); o.y = r2v | (r3v << 16);
            o.z = r4v | (r5v << 16); o.w = r6v | (r7v << 16);
            reinterpret_cast<uint4*>(outp)[(size_t)wid * 8 + sub] = o;
        }
    }
}

// ---- bucket-sort body (shared arrays passed in) ---------------------------------
__device__ __forceinline__ void bucket_sort_body(int b, int t,
        const unsigned* __restrict__ pairs, const int* __restrict__ gcur,
        unsigned short* __restrict__ stails, int* __restrict__ starts, int* __restrict__ ends,
        unsigned short* staging, int* cnt_l, int* scan_s, int* cur) {
    int node0 = b * BNODES;
    int nn = min(BNODES, NN - node0);
    int cnt = min(gcur[b], CAP);
    cnt_l[t] = 0;
    __syncthreads();
    const unsigned* P = pairs + (size_t)b * CAP;
    for (int i = t; i < cnt; i += 256) {
        int local = (int)(P[i] >> 15) - node0;
        atomicAdd(&cnt_l[local], 1);
    }
    __syncthreads();
    int v = cnt_l[t];
    scan_s[t] = v;
    __syncthreads();
    for (int off = 1; off < 256; off <<= 1) {
        int tv = (t >= off) ? scan_s[t - off] : 0;
        __syncthreads();
        scan_s[t] += tv;
        __syncthreads();
    }
    int excl = scan_s[t] - v;
    cur[t] = excl;
    if (t < nn) {
        starts[node0 + t] = b * CAP + excl;
        ends[node0 + t]   = b * CAP + excl + v;
    }
    __syncthreads();
    for (int i = t; i < cnt; i += 256) {
        unsigned p = P[i];
        int local = (int)(p >> 15) - node0;
        int pos = atomicAdd(&cur[local], 1);
        staging[pos] = (unsigned short)(p & 0x7FFFu);
    }
    __syncthreads();
    for (int i = t; i < cnt; i += 256)
        stails[(size_t)b * CAP + i] = staging[i];
}

// ---- cooperative fused kernel: bucket_sort -> hop1 -> hop2 ----------------------
__global__ void __launch_bounds__(256, 4) fused_coop(
        const unsigned* __restrict__ pairs, const int* __restrict__ gcur,
        unsigned short* __restrict__ stails, int* __restrict__ starts, int* __restrict__ ends,
        const unsigned short* __restrict__ off0, unsigned short* __restrict__ off1,
        float* __restrict__ out2) {
    cg::grid_group grid = cg::this_grid();
    __shared__ unsigned short staging[CAP];
    __shared__ int cnt_l[256];
    __shared__ int scan_s[256];
    __shared__ int cur[256];
    int t = threadIdx.x;
    int lane = t & 63;
    // phase 1: CSR build
    for (int b = blockIdx.x; b < NB; b += gridDim.x) {
        bucket_sort_body(b, t, pairs, gcur, stails, starts, ends, staging, cnt_l, scan_s, cur);
        __syncthreads();
    }
    __threadfence();
    grid.sync();
    // phase 2: hop 1 over all NN nodes (bf16 out)
    const int nvb1 = (NN + 3) / 4;
    for (int vb = blockIdx.x; vb < nvb1; vb += gridDim.x)
        hop_node<false>(vb * 4 + (t >> 6), lane, off0, starts, ends, stails, off1, NN);
    __threadfence();
    grid.sync();
    // phase 3: hop 2 over visit nodes (f32 out)
    const int nvb2 = (NV + 3) / 4;
    for (int vb = blockIdx.x; vb < nvb2; vb += gridDim.x)
        hop_node<true>(vb * 4 + (t >> 6), lane, off1, starts, ends, stails, out2, NV);
}

// ---- fallback standalone kernels (used only if coop launch fails) ---------------
__global__ void bucket_sort_kernel(const unsigned* __restrict__ pairs, const int* __restrict__ gcur,
                                   unsigned short* __restrict__ stails,
                                   int* __restrict__ starts, int* __restrict__ ends) {
    __shared__ unsigned short staging[CAP];
    __shared__ int cnt_l[256];
    __shared__ int scan_s[256];
    __shared__ int cur[256];
    bucket_sort_body(blockIdx.x, threadIdx.x, pairs, gcur, stails, starts, ends,
                     staging, cnt_l, scan_s, cur);
}

template<bool F32OUT>
__global__ __launch_bounds__(256) void hop_kernel(
        const unsigned short* __restrict__ prev,
        const int* __restrict__ starts, const int* __restrict__ ends,
        const unsigned short* __restrict__ stails, void* __restrict__ outp, int nNodes) {
    hop_node<F32OUT>(blockIdx.x * 4 + (threadIdx.x >> 6), threadIdx.x & 63,
                     prev, starts, ends, stails, outp, nNodes);
}

extern "C" void kernel_launch(void* const* d_in, const int* in_sizes, int n_in,
                              void* d_out, int out_size, void* d_ws, size_t ws_size,
                              hipStream_t stream) {
    const float* visit_offset = (const float*)d_in[1];
    const float* ccs_offset   = (const float*)d_in[3];
    const float* icd_offset   = (const float*)d_in[5];
    const int*   head         = (const int*)d_in[6];
    const int*   tail         = (const int*)d_in[7];
    float*       out          = (float*)d_out;

    char* ws = (char*)d_ws;
    unsigned short* off0   = (unsigned short*)(ws);                        // 3.88 MB
    unsigned short* off1   = (unsigned short*)(ws + (4u << 20));           // 3.88 MB
    unsigned*       pairs  = (unsigned*)      (ws + (8u << 20));           // 5.24 MB
    unsigned short* stails = (unsigned short*)(ws + (14u << 20));          // 2.62 MB
    int*            starts = (int*)           (ws + (17u << 20));          // 121 KB
    int*            ends   = (int*)           (ws + (17u << 20) + (256u << 10));
    int*            gcur   = (int*)           (ws + (17u << 20) + (512u << 10));
    float*          out2   = out + (size_t)NV * D;

    hipMemsetAsync(gcur, 0, NB * sizeof(int), stream);

    init_bin_kernel<<<(NN * 16 + 255) / 256, 256, 0, stream>>>(
        (const float4*)visit_offset, (const float4*)ccs_offset, (const float4*)icd_offset,
        off0, (float4*)out, head, tail, gcur, pairs);

    void* args[] = { (void*)&pairs, (void*)&gcur, (void*)&stails, (void*)&starts,
                     (void*)&ends, (void*)&off0, (void*)&off1, (void*)&out2 };
    hipError_t err = hipLaunchCooperativeKernel((const void*)fused_coop,
                                                dim3(COOP_BLOCKS), dim3(256), args, 0, stream);
    if (err != hipSuccess) {
        // fallback: sequential launches
        bucket_sort_kernel<<<NB, 256, 0, stream>>>(pairs, gcur, stails, starts, ends);
        hop_kernel<false><<<(NN + 3) / 4, 256, 0, stream>>>(off0, starts, ends, stails, off1, NN);
        hop_kernel<true><<<(NV + 3) / 4, 256, 0, stream>>>(off1, starts, ends, stails, out2, NV);
    }
}